// Round 3
// baseline (340.873 us; speedup 1.0000x reference)
//
#include <hip/hip_runtime.h>
#include <stdint.h>
#include <math.h>

#define HD 512
#define ID 1408
#define NEXP 8
#define NTOK 2048
#define NPAIRS 4096
#define NROWS 6144   // 4096 routed pairs + 2048 shared rows

typedef unsigned short u16;
typedef __attribute__((ext_vector_type(8))) __bf16 bf16x8;
typedef __attribute__((ext_vector_type(4))) float f32x4;

__device__ __forceinline__ u16 f2bf(float f) {
  union { float f; uint32_t u; } v; v.f = f;
  uint32_t u = v.u;
  u += 0x7FFFu + ((u >> 16) & 1u);   // RNE
  return (u16)(u >> 16);
}

// ------------- gate: fp32 logits, softmax, top-2; fused x->bf16 cast -------------
__global__ __launch_bounds__(256) void gate_kernel(
    const float* __restrict__ x, const float* __restrict__ gw,
    u16* __restrict__ xg, float* __restrict__ scores,
    float* __restrict__ topw, int* __restrict__ topidx) {
  int t = blockIdx.x * 4 + (threadIdx.x >> 6);
  int lane = threadIdx.x & 63;
  const float4* xp = (const float4*)(x + (size_t)t * HD + lane * 8);
  float4 v0 = xp[0], v1 = xp[1];
  float xv[8] = {v0.x, v0.y, v0.z, v0.w, v1.x, v1.y, v1.z, v1.w};
  ushort4 o0, o1;
  o0.x = f2bf(xv[0]); o0.y = f2bf(xv[1]); o0.z = f2bf(xv[2]); o0.w = f2bf(xv[3]);
  o1.x = f2bf(xv[4]); o1.y = f2bf(xv[5]); o1.z = f2bf(xv[6]); o1.w = f2bf(xv[7]);
  ushort4* xo = (ushort4*)(xg + (size_t)t * HD + lane * 8);
  xo[0] = o0; xo[1] = o1;
  float sc[8];
#pragma unroll
  for (int e = 0; e < 8; ++e) {
    const float4* gp = (const float4*)(gw + e * HD + lane * 8);
    float4 g0 = gp[0], g1 = gp[1];
    float p = xv[0] * g0.x + xv[1] * g0.y + xv[2] * g0.z + xv[3] * g0.w
            + xv[4] * g1.x + xv[5] * g1.y + xv[6] * g1.z + xv[7] * g1.w;
#pragma unroll
    for (int o = 32; o; o >>= 1) p += __shfl_xor(p, o);
    sc[e] = p;
  }
  float m = sc[0];
#pragma unroll
  for (int e = 1; e < 8; ++e) m = fmaxf(m, sc[e]);
  float ssum = 0.f;
#pragma unroll
  for (int e = 0; e < 8; ++e) { sc[e] = expf(sc[e] - m); ssum += sc[e]; }
  float is = 1.f / ssum;
#pragma unroll
  for (int e = 0; e < 8; ++e) sc[e] *= is;
  int e0 = 0; float v0s = sc[0];
#pragma unroll
  for (int e = 1; e < 8; ++e) if (sc[e] > v0s) { v0s = sc[e]; e0 = e; }
  int e1 = -1; float v1s = -1.f;
#pragma unroll
  for (int e = 0; e < 8; ++e) if (e != e0 && sc[e] > v1s) { v1s = sc[e]; e1 = e; }
  if (lane == 0) {
#pragma unroll
    for (int e = 0; e < 8; ++e) scores[t * 8 + e] = sc[e];
    float d = v0s + v1s + 1e-20f;
    topw[t * 2] = v0s / d; topw[t * 2 + 1] = v1s / d;
    topidx[t * 2] = e0; topidx[t * 2 + 1] = e1;
  }
}

// ------- scatter: counts -> offsets -> permutation + inv map + aux loss -------
__global__ __launch_bounds__(1024) void scatter_kernel(
    const int* __restrict__ topidx, const float* __restrict__ scores,
    int* __restrict__ pairTok, int* __restrict__ inv,
    int* __restrict__ segOff, int* __restrict__ segN, float* __restrict__ auxout) {
  __shared__ int cnt[8], offs[8], cur[8];
  __shared__ float partS[1024];
  __shared__ int partC[1024];
  int tid = threadIdx.x;
  if (tid < 8) { cnt[tid] = 0; cur[tid] = 0; }
  __syncthreads();
  for (int p = tid; p < NPAIRS; p += 1024) atomicAdd(&cnt[topidx[p]], 1);
  __syncthreads();
  if (tid == 0) {
    int run = 0;
    for (int e = 0; e < 8; ++e) { offs[e] = run; segOff[e] = run; segN[e] = cnt[e]; run += cnt[e]; }
    segOff[8] = NPAIRS; segN[8] = NTOK;
  }
  __syncthreads();
  for (int p = tid; p < NPAIRS; p += 1024) {
    int e = topidx[p];
    int pos = offs[e] + atomicAdd(&cur[e], 1);
    pairTok[pos] = p >> 1;
    inv[p] = pos;
  }
  // aux loss (deterministic tree reduction)
  int c = tid & 15, g = tid >> 4;       // c: (b,e) combo, g: 0..63
  int b = c >> 3, e = c & 7;
  float ls = 0.f; int lc = 0;
  for (int jj = 0; jj < 16; ++jj) {
    int t = b * 1024 + (g + jj * 64);
    lc += (topidx[t * 2] == e) + (topidx[t * 2 + 1] == e);
    ls += scores[t * 8 + e];
  }
  partS[c * 64 + g] = ls; partC[c * 64 + g] = lc;
  __syncthreads();
  for (int st = 32; st; st >>= 1) {
    if (g < st) {
      partS[c * 64 + g] += partS[c * 64 + g + st];
      partC[c * 64 + g] += partC[c * 64 + g + st];
    }
    __syncthreads();
  }
  if (tid == 0) {
    float aux = 0.f;
    for (int cc = 0; cc < 16; ++cc)
      aux += ((float)partC[cc * 64] / 256.0f) * (partS[cc * 64] / 1024.0f);
    *auxout = aux * 0.5f * 0.1f;
  }
}

// ---------- fused transpose+cast, 32r x 64c tiles, packed ushort2 writes ----------
// slabs: 0-7 Wg, 8-15 Wu, 16-23 Wd, 24 Wgs, 25 Wus, 26 Wds; 352 tiles each
__global__ __launch_bounds__(256) void transpose_all_kernel(
    const float* __restrict__ Wg, const float* __restrict__ Wu, const float* __restrict__ Wd,
    const float* __restrict__ Wgs, const float* __restrict__ Wus, const float* __restrict__ Wds,
    u16* __restrict__ Wgt, u16* __restrict__ Wut, u16* __restrict__ Wdt,
    u16* __restrict__ Wgst, u16* __restrict__ Wust, u16* __restrict__ Wdst) {
  __shared__ float tile[32][65];
  int bx = blockIdx.x;
  int slab = bx / 352;
  int t = bx % 352;
  const float* src; u16* dst; int R, C;
  if (slab < 8)       { R = 512;  C = 1408; src = Wg + (size_t)slab * R * C;        dst = Wgt + (size_t)slab * R * C; }
  else if (slab < 16) { R = 512;  C = 1408; src = Wu + (size_t)(slab - 8) * R * C;  dst = Wut + (size_t)(slab - 8) * R * C; }
  else if (slab < 24) { R = 1408; C = 512;  src = Wd + (size_t)(slab - 16) * R * C; dst = Wdt + (size_t)(slab - 16) * R * C; }
  else if (slab == 24){ R = 512;  C = 1408; src = Wgs; dst = Wgst; }
  else if (slab == 25){ R = 512;  C = 1408; src = Wus; dst = Wust; }
  else                { R = 1408; C = 512;  src = Wds; dst = Wdst; }
  int C64 = C >> 6;
  int c0 = (t % C64) * 64, r0 = (t / C64) * 32;
  int tid = threadIdx.x;
  // read: 16 lanes span 64 cols (float4 each), 16 rows per pass
  int c4 = tid & 15, rr = tid >> 4;
#pragma unroll
  for (int it = 0; it < 2; ++it) {
    int r = rr + it * 16;
    float4 v = *(const float4*)(src + (size_t)(r0 + r) * C + c0 + c4 * 4);
    tile[r][c4 * 4 + 0] = v.x; tile[r][c4 * 4 + 1] = v.y;
    tile[r][c4 * 4 + 2] = v.z; tile[r][c4 * 4 + 3] = v.w;
  }
  __syncthreads();
  // write: lane owns (col, row-pair) -> packed 2xbf16 (4B) store
  int rp = tid & 15, cc = tid >> 4;
#pragma unroll
  for (int it = 0; it < 4; ++it) {
    int c = cc + it * 16;
    uint32_t lo = f2bf(tile[2 * rp][c]);
    uint32_t hi = f2bf(tile[2 * rp + 1][c]);
    *(uint32_t*)(dst + (size_t)(c0 + c) * R + r0 + 2 * rp) = lo | (hi << 16);
  }
}

// --------- GEMM1 (LDS-free): act = silu(x@Wg)*(x@Wu), direct global->reg MFMA ---------
// tile 128(M) x 64(N), 4 waves (2x2), wave = 64x32 per tensor
// grid 3168 = 16 mt x 22 nt x 9 s, XCD-swizzled (mt fastest)
__global__ __launch_bounds__(256) void gemm1_kernel(
    const u16* __restrict__ Xg,
    const u16* __restrict__ Wgt, const u16* __restrict__ Wut,
    const u16* __restrict__ Wgst, const u16* __restrict__ Wust,
    const int* __restrict__ pairTok, const int* __restrict__ segOff,
    const int* __restrict__ segN, u16* __restrict__ act) {
  int lin = blockIdx.x;
  int wg = (lin & 7) * 396 + (lin >> 3);     // 3168/8 = 396, bijective
  int mt = wg & 15;
  int rest = wg >> 4;
  int nt = rest % 22;
  int s = rest / 22;
  int off = segOff[s], n = segN[s];
  if (mt * 128 >= n) return;
  const u16* Bg = (s < 8) ? Wgt + (size_t)s * ID * HD : Wgst;
  const u16* Bu = (s < 8) ? Wut + (size_t)s * ID * HD : Wust;

  int tid = threadIdx.x;
  int w = tid >> 6, lane = tid & 63;
  int wm = w >> 1, wn = w & 1;
  int l15 = lane & 15, lh = lane >> 4;

  // per-lane A row gather (token indirection), clamped
  int pmax = off + n - 1;
  const u16* aptr[4];
#pragma unroll
  for (int i = 0; i < 4; ++i) {
    int pr = off + mt * 128 + wm * 64 + i * 16 + l15;
    if (pr > pmax) pr = pmax;
    int tok = (s < 8) ? pairTok[pr] : (pr - NPAIRS);
    aptr[i] = Xg + (size_t)tok * HD + lh * 8;
  }
  const u16* bgp[2]; const u16* bup[2];
#pragma unroll
  for (int j = 0; j < 2; ++j) {
    int ncol = nt * 64 + wn * 32 + j * 16 + l15;
    bgp[j] = Bg + (size_t)ncol * HD + lh * 8;
    bup[j] = Bu + (size_t)ncol * HD + lh * 8;
  }

  f32x4 accg[4][2], accu[4][2];
  f32x4 zz = {0.f, 0.f, 0.f, 0.f};
#pragma unroll
  for (int i = 0; i < 4; ++i)
#pragma unroll
    for (int j = 0; j < 2; ++j) { accg[i][j] = zz; accu[i][j] = zz; }

  bf16x8 a[2][4], bg[2][2], bu[2][2];
#pragma unroll
  for (int i = 0; i < 4; ++i) a[0][i] = *(const bf16x8*)(aptr[i]);
#pragma unroll
  for (int j = 0; j < 2; ++j) {
    bg[0][j] = *(const bf16x8*)(bgp[j]);
    bu[0][j] = *(const bf16x8*)(bup[j]);
  }
#pragma unroll
  for (int kt = 0; kt < 16; ++kt) {
    int cur = kt & 1, nxt = cur ^ 1;
    if (kt < 15) {
      int ko = (kt + 1) * 32;
#pragma unroll
      for (int i = 0; i < 4; ++i) a[nxt][i] = *(const bf16x8*)(aptr[i] + ko);
#pragma unroll
      for (int j = 0; j < 2; ++j) {
        bg[nxt][j] = *(const bf16x8*)(bgp[j] + ko);
        bu[nxt][j] = *(const bf16x8*)(bup[j] + ko);
      }
    }
#pragma unroll
    for (int i = 0; i < 4; ++i)
#pragma unroll
      for (int j = 0; j < 2; ++j) {
        accg[i][j] = __builtin_amdgcn_mfma_f32_16x16x32_bf16(a[cur][i], bg[cur][j], accg[i][j], 0, 0, 0);
        accu[i][j] = __builtin_amdgcn_mfma_f32_16x16x32_bf16(a[cur][i], bu[cur][j], accu[i][j], 0, 0, 0);
      }
  }
  int base_row = mt * 128;
#pragma unroll
  for (int i = 0; i < 4; ++i)
#pragma unroll
    for (int j = 0; j < 2; ++j)
#pragma unroll
      for (int r = 0; r < 4; ++r) {
        int rl = wm * 64 + i * 16 + lh * 4 + r;
        if (base_row + rl < n) {
          int col = nt * 64 + wn * 32 + j * 16 + l15;
          float gv = accg[i][j][r], uv = accu[i][j][r];
          float av = (gv / (1.f + expf(-gv))) * uv;
          act[(size_t)(off + base_row + rl) * ID + col] = f2bf(av);
        }
      }
}

// --------- GEMM2 (LDS-free): ybuf = act @ Wd^T, direct global->reg MFMA ---------
// tile 64(M) x 128(N), 4 waves (2x2), wave = 32x64
// grid 1152 = 32 mt x 4 nt x 9 s, XCD-swizzled (mt fastest)
__global__ __launch_bounds__(256) void gemm2_kernel(
    const u16* __restrict__ act,
    const u16* __restrict__ Wdt, const u16* __restrict__ Wdst,
    const int* __restrict__ segOff, const int* __restrict__ segN,
    float* __restrict__ ybuf) {
  int lin = blockIdx.x;
  int wg = (lin & 7) * 144 + (lin >> 3);     // 1152/8 = 144, bijective
  int mt = wg & 31;
  int rest = wg >> 5;
  int nt = rest & 3;
  int s = rest >> 2;
  int off = segOff[s], n = segN[s];
  if (mt * 64 >= n) return;
  const u16* B = (s < 8) ? Wdt + (size_t)s * HD * ID : Wdst;  // [512][1408]

  int tid = threadIdx.x;
  int w = tid >> 6, lane = tid & 63;
  int wm = w >> 1, wn = w & 1;
  int l15 = lane & 15, lh = lane >> 4;

  int pmax = off + n - 1;
  const u16* aptr[2];
#pragma unroll
  for (int i = 0; i < 2; ++i) {
    int p = off + mt * 64 + wm * 32 + i * 16 + l15;
    if (p > pmax) p = pmax;
    aptr[i] = act + (size_t)p * ID + lh * 8;
  }
  const u16* bptr[4];
#pragma unroll
  for (int j = 0; j < 4; ++j) {
    int hcol = nt * 128 + wn * 64 + j * 16 + l15;
    bptr[j] = B + (size_t)hcol * ID + lh * 8;
  }

  f32x4 acc[2][4];
  f32x4 zz = {0.f, 0.f, 0.f, 0.f};
#pragma unroll
  for (int i = 0; i < 2; ++i)
#pragma unroll
    for (int j = 0; j < 4; ++j) acc[i][j] = zz;

  bf16x8 a[2][2], b[2][4];
#pragma unroll
  for (int i = 0; i < 2; ++i) a[0][i] = *(const bf16x8*)(aptr[i]);
#pragma unroll
  for (int j = 0; j < 4; ++j) b[0][j] = *(const bf16x8*)(bptr[j]);
#pragma unroll 2
  for (int kt = 0; kt < 44; ++kt) {
    int cur = kt & 1, nxt = cur ^ 1;
    if (kt < 43) {
      int ko = (kt + 1) * 32;
#pragma unroll
      for (int i = 0; i < 2; ++i) a[nxt][i] = *(const bf16x8*)(aptr[i] + ko);
#pragma unroll
      for (int j = 0; j < 4; ++j) b[nxt][j] = *(const bf16x8*)(bptr[j] + ko);
    }
#pragma unroll
    for (int i = 0; i < 2; ++i)
#pragma unroll
      for (int j = 0; j < 4; ++j)
        acc[i][j] = __builtin_amdgcn_mfma_f32_16x16x32_bf16(a[cur][i], b[cur][j], acc[i][j], 0, 0, 0);
  }
  int base_row = mt * 64;
#pragma unroll
  for (int i = 0; i < 2; ++i)
#pragma unroll
    for (int j = 0; j < 4; ++j)
#pragma unroll
      for (int r = 0; r < 4; ++r) {
        int rl = wm * 32 + i * 16 + lh * 4 + r;
        if (base_row + rl < n) {
          int col = nt * 128 + wn * 64 + j * 16 + l15;
          ybuf[(size_t)(off + base_row + rl) * HD + col] = acc[i][j][r];
        }
      }
}

// --------- combine: out[t] = w0*y(pair0) + w1*y(pair1) + y(shared) ---------
__global__ void combine_kernel(const float* __restrict__ ybuf, const float* __restrict__ topw,
                               const int* __restrict__ inv, float* __restrict__ out) {
  int t = blockIdx.x;
  int hd = threadIdx.x;  // 128 float4 lanes
  int i0 = inv[t * 2], i1 = inv[t * 2 + 1];
  float w0 = topw[t * 2], w1 = topw[t * 2 + 1];
  const float4* y4 = (const float4*)ybuf;
  float4 a = y4[(size_t)i0 * 128 + hd];
  float4 b = y4[(size_t)i1 * 128 + hd];
  float4 c = y4[(size_t)(NPAIRS + t) * 128 + hd];
  float4 o;
  o.x = w0 * a.x + w1 * b.x + c.x;
  o.y = w0 * a.y + w1 * b.y + c.y;
  o.z = w0 * a.z + w1 * b.z + c.z;
  o.w = w0 * a.w + w1 * b.w + c.w;
  ((float4*)out)[(size_t)t * 128 + hd] = o;
}

extern "C" void kernel_launch(void* const* d_in, const int* in_sizes, int n_in,
                              void* d_out, int out_size, void* d_ws, size_t ws_size,
                              hipStream_t stream) {
  const float* x   = (const float*)d_in[0];
  const float* gw  = (const float*)d_in[1];
  const float* Wg  = (const float*)d_in[2];
  const float* Wu  = (const float*)d_in[3];
  const float* Wd  = (const float*)d_in[4];
  const float* Wgs = (const float*)d_in[5];
  const float* Wus = (const float*)d_in[6];
  const float* Wds = (const float*)d_in[7];
  float* out = (float*)d_out;

  if (ws_size < (size_t)72 * 1024 * 1024) return;

  char* ws = (char*)d_ws;
  size_t o = 0;
  auto alloc = [&](size_t bytes) { char* p = ws + o; o += (bytes + 255) & ~(size_t)255; return p; };
  u16* Xg    = (u16*)alloc((size_t)NTOK * HD * 2);
  u16* Wgt   = (u16*)alloc((size_t)NEXP * ID * HD * 2);
  u16* Wut   = (u16*)alloc((size_t)NEXP * ID * HD * 2);
  u16* Wdt   = (u16*)alloc((size_t)NEXP * HD * ID * 2);
  u16* Wgst  = (u16*)alloc((size_t)ID * HD * 2);
  u16* Wust  = (u16*)alloc((size_t)ID * HD * 2);
  u16* Wdst  = (u16*)alloc((size_t)HD * ID * 2);
  u16* act   = (u16*)alloc((size_t)NROWS * ID * 2);
  float* ybuf   = (float*)alloc((size_t)NROWS * HD * 4);
  float* scores = (float*)alloc((size_t)NTOK * 8 * 4);
  float* topw   = (float*)alloc((size_t)NTOK * 2 * 4);
  int* topidx   = (int*)alloc((size_t)NTOK * 2 * 4);
  int* pairTok  = (int*)alloc((size_t)NPAIRS * 4);
  int* inv      = (int*)alloc((size_t)NPAIRS * 4);
  int* segOff   = (int*)alloc(64);
  int* segN     = (int*)alloc(64);

  gate_kernel<<<NTOK / 4, 256, 0, stream>>>(x, gw, Xg, scores, topw, topidx);
  scatter_kernel<<<1, 1024, 0, stream>>>(topidx, scores, pairTok, inv, segOff, segN,
                                         out + (size_t)NTOK * HD);
  transpose_all_kernel<<<27 * 352, 256, 0, stream>>>(Wg, Wu, Wd, Wgs, Wus, Wds,
                                                     Wgt, Wut, Wdt, Wgst, Wust, Wdst);
  gemm1_kernel<<<16 * 22 * 9, 256, 0, stream>>>(Xg, Wgt, Wut, Wgst, Wust,
                                                pairTok, segOff, segN, act);
  gemm2_kernel<<<32 * 4 * 9, 256, 0, stream>>>(act, Wdt, Wdst, segOff, segN, ybuf);
  combine_kernel<<<NTOK, 128, 0, stream>>>(ybuf, topw, inv, out);
}

// Round 4
// 145.477 us; speedup vs baseline: 2.3431x; 2.3431x over previous
//
#include <hip/hip_runtime.h>
#include <stdint.h>
#include <math.h>

#define HD 512
#define ID 1408
#define NTOK 2048
#define NPAIRS 4096
#define PADCAP 5120
#define SHOFF 5120
#define TOTROWS 7168

typedef unsigned short u16;
typedef __attribute__((ext_vector_type(8))) __bf16 bf16x8;
typedef __attribute__((ext_vector_type(4))) float f32x4;

__device__ __forceinline__ u16 f2bf(float f) {
  union { float f; uint32_t u; } v; v.f = f;
  uint32_t u = v.u;
  u += 0x7FFFu + ((u >> 16) & 1u);   // RNE
  return (u16)(u >> 16);
}

__device__ __forceinline__ void gll16(const void* g, void* l) {
  __builtin_amdgcn_global_load_lds((const __attribute__((address_space(1))) void*)g,
                                   (__attribute__((address_space(3))) void*)l, 16, 0, 0);
}

// ------------- gate: fp32 logits, softmax, top-2; fused x->bf16 cast -------------
__global__ __launch_bounds__(256) void gate_kernel(
    const float* __restrict__ x, const float* __restrict__ gw,
    u16* __restrict__ xg, float* __restrict__ scores,
    float* __restrict__ topw, int* __restrict__ topidx) {
  int t = blockIdx.x * 4 + (threadIdx.x >> 6);
  int lane = threadIdx.x & 63;
  const float4* xp = (const float4*)(x + (size_t)t * HD + lane * 8);
  float4 v0 = xp[0], v1 = xp[1];
  float xv[8] = {v0.x, v0.y, v0.z, v0.w, v1.x, v1.y, v1.z, v1.w};
  ushort4 o0, o1;
  o0.x = f2bf(xv[0]); o0.y = f2bf(xv[1]); o0.z = f2bf(xv[2]); o0.w = f2bf(xv[3]);
  o1.x = f2bf(xv[4]); o1.y = f2bf(xv[5]); o1.z = f2bf(xv[6]); o1.w = f2bf(xv[7]);
  ushort4* xo = (ushort4*)(xg + (size_t)t * HD + lane * 8);
  xo[0] = o0; xo[1] = o1;
  float sc[8];
#pragma unroll
  for (int e = 0; e < 8; ++e) {
    const float4* gp = (const float4*)(gw + e * HD + lane * 8);
    float4 g0 = gp[0], g1 = gp[1];
    float p = xv[0] * g0.x + xv[1] * g0.y + xv[2] * g0.z + xv[3] * g0.w
            + xv[4] * g1.x + xv[5] * g1.y + xv[6] * g1.z + xv[7] * g1.w;
#pragma unroll
    for (int o = 32; o; o >>= 1) p += __shfl_xor(p, o);
    sc[e] = p;
  }
  float m = sc[0];
#pragma unroll
  for (int e = 1; e < 8; ++e) m = fmaxf(m, sc[e]);
  float ssum = 0.f;
#pragma unroll
  for (int e = 0; e < 8; ++e) { sc[e] = expf(sc[e] - m); ssum += sc[e]; }
  float is = 1.f / ssum;
#pragma unroll
  for (int e = 0; e < 8; ++e) sc[e] *= is;
  int e0 = 0; float v0s = sc[0];
#pragma unroll
  for (int e = 1; e < 8; ++e) if (sc[e] > v0s) { v0s = sc[e]; e0 = e; }
  int e1 = -1; float v1s = -1.f;
#pragma unroll
  for (int e = 0; e < 8; ++e) if (e != e0 && sc[e] > v1s) { v1s = sc[e]; e1 = e; }
  if (lane == 0) {
#pragma unroll
    for (int e = 0; e < 8; ++e) scores[t * 8 + e] = sc[e];
    float d = v0s + v1s + 1e-20f;
    topw[t * 2] = v0s / d; topw[t * 2 + 1] = v1s / d;
    topidx[t * 2] = e0; topidx[t * 2 + 1] = e1;
  }
}

// ------- scatter: counts -> padded offsets -> permutation + tile table + aux -------
__global__ __launch_bounds__(1024) void scatter_kernel(
    const int* __restrict__ topidx, const float* __restrict__ scores,
    int* __restrict__ pairTok, int* __restrict__ inv,
    int* __restrict__ segTileStart, int* __restrict__ tileSeg,
    float* __restrict__ auxout) {
  __shared__ int cnt[8], offs[8], cur[8];
  __shared__ float partS[1024];
  __shared__ int partC[1024];
  int tid = threadIdx.x;
  if (tid < 8) { cnt[tid] = 0; cur[tid] = 0; }
  __syncthreads();
  for (int p = tid; p < PADCAP; p += 1024) pairTok[p] = 0;
  for (int p = tid; p < NPAIRS; p += 1024) atomicAdd(&cnt[topidx[p]], 1);
  __syncthreads();
  if (tid == 0) {
    int run = 0;
    for (int e = 0; e < 8; ++e) {
      offs[e] = run;
      segTileStart[e] = run >> 7;
      run += ((cnt[e] + 127) >> 7) << 7;     // pad each segment to mult of 128
    }
    segTileStart[8] = run >> 7;
    int RT = run >> 7;
    for (int mt = 0; mt < 56; ++mt) {
      int sgv;
      if (mt >= 40) sgv = 8;
      else if (mt >= RT) sgv = -1;
      else {
        sgv = 0;
        for (int e = 7; e >= 1; --e) if (mt >= (offs[e] >> 7)) { sgv = e; break; }
      }
      tileSeg[mt] = sgv;
    }
  }
  __syncthreads();
  for (int p = tid; p < NPAIRS; p += 1024) {
    int e = topidx[p];
    int pos = offs[e] + atomicAdd(&cur[e], 1);
    pairTok[pos] = p >> 1;
    inv[p] = pos;
  }
  // aux loss (deterministic tree reduction)
  int c = tid & 15, g = tid >> 4;
  int b = c >> 3, e = c & 7;
  float ls = 0.f; int lc = 0;
  for (int jj = 0; jj < 16; ++jj) {
    int t = b * 1024 + (g + jj * 64);
    lc += (topidx[t * 2] == e) + (topidx[t * 2 + 1] == e);
    ls += scores[t * 8 + e];
  }
  partS[c * 64 + g] = ls; partC[c * 64 + g] = lc;
  __syncthreads();
  for (int st = 32; st; st >>= 1) {
    if (g < st) {
      partS[c * 64 + g] += partS[c * 64 + g + st];
      partC[c * 64 + g] += partC[c * 64 + g + st];
    }
    __syncthreads();
  }
  if (tid == 0) {
    float aux = 0.f;
    for (int cc = 0; cc < 16; ++cc)
      aux += ((float)partC[cc * 64] / 256.0f) * (partS[cc * 64] / 1024.0f);
    *auxout = aux * 0.5f * 0.1f;
  }
}

// --------- GEMM1: W-panel LDS-resident, fused f32->bf16 transpose staging ---------
// block = (nt of 32 cols, sidx of 12 segs); m-loop over segment tiles. 80KB LDS.
__global__ __launch_bounds__(256, 2) void gemm1_kernel(
    const u16* __restrict__ Xg,
    const float* __restrict__ Wg, const float* __restrict__ Wu,
    const float* __restrict__ Wgs, const float* __restrict__ Wus,
    const int* __restrict__ pairTok, const int* __restrict__ segTileStart,
    u16* __restrict__ act) {
  __shared__ __align__(16) u16 WgL[32 * 512];   // [n][k], XOR-swizzled, 32KB
  __shared__ __align__(16) u16 WuL[32 * 512];
  __shared__ __align__(16) u16 Al[2][128 * 32]; // A dbuf, 2x8KB
  int lin = blockIdx.x;
  int wg = (lin & 7) * 66 + (lin >> 3);        // 528/8 = 66, bijective XCD chunks
  int nt = wg % 44;
  int sidx = wg / 44;
  int t0, t1;
  const float *wgsrc, *wusrc;
  if (sidx < 8) {
    t0 = segTileStart[sidx]; t1 = segTileStart[sidx + 1];
    wgsrc = Wg + (size_t)sidx * HD * ID; wusrc = Wu + (size_t)sidx * HD * ID;
  } else {
    t0 = 40 + (sidx - 8) * 4; t1 = t0 + 4;
    wgsrc = Wgs; wusrc = Wus;
  }
  if (t0 >= t1) return;
  int tid = threadIdx.x;
  int n0 = nt * 32;
  // ---- stage W panels once: read f32 [k][n] coalesced, write bf16 [n][k] swizzled ----
  {
    int n = tid & 31, kb = tid >> 5;
    const float* pg = wgsrc + n0 + n;
    const float* pu = wusrc + n0 + n;
    int swz = (n & 7) << 4;
    for (int jj = 0; jj < 8; ++jj) {
      int k = kb * 64 + jj * 8;
      bf16x8 vg, vu;
#pragma unroll
      for (int q = 0; q < 8; ++q) {
        vg[q] = (__bf16)pg[(k + q) * ID];
        vu[q] = (__bf16)pu[(k + q) * ID];
      }
      int byo = (n * 1024 + k * 2) ^ swz;
      *(bf16x8*)((char*)WgL + byo) = vg;
      *(bf16x8*)((char*)WuL + byo) = vu;
    }
  }
  __syncthreads();
  int w = tid >> 6, lane = tid & 63;
  int wm = w >> 1, wn = w & 1;
  int l15 = lane & 15, lh = lane >> 4;
  int mA = tid >> 2, slot = tid & 3;
  int nloc = wn * 16 + l15;
  int ncol = n0 + nloc;
  int bswz = (nloc & 7) << 4;

  for (int mt = t0; mt < t1; ++mt) {
    int g0 = mt * 128;
    const u16* srcA[2];
#pragma unroll
    for (int c = 0; c < 2; ++c) {
      int m = c * 64 + mA;
      int row = g0 + m;
      int tok = (sidx < 8) ? pairTok[row] : (row - SHOFF);
      srcA[c] = Xg + (size_t)tok * HD + (slot ^ (m & 3)) * 8;  // pre-swizzled source
    }
    auto STAGEA = [&](int nb, int kt) {
      int ko = kt * 32;
#pragma unroll
      for (int c = 0; c < 2; ++c)
        gll16(srcA[c] + ko, (char*)Al[nb] + c * 4096 + w * 1024);
    };
    STAGEA(0, 0);
    f32x4 accg[4], accu[4];
    f32x4 zz = {0.f, 0.f, 0.f, 0.f};
#pragma unroll
    for (int i = 0; i < 4; ++i) { accg[i] = zz; accu[i] = zz; }
    __syncthreads();
    for (int kt = 0; kt < 16; ++kt) {
      int cb = kt & 1;
      if (kt < 15) STAGEA(cb ^ 1, kt + 1);
      int kby = kt * 64 + lh * 16;
      bf16x8 bgf = *(const bf16x8*)((char*)WgL + ((nloc * 1024 + kby) ^ bswz));
      bf16x8 buv = *(const bf16x8*)((char*)WuL + ((nloc * 1024 + kby) ^ bswz));
      bf16x8 a[4];
#pragma unroll
      for (int i = 0; i < 4; ++i) {
        int mloc = wm * 64 + i * 16 + l15;
        a[i] = *(const bf16x8*)((char*)Al[cb] + ((mloc * 64 + lh * 16) ^ ((mloc & 3) << 4)));
      }
#pragma unroll
      for (int i = 0; i < 4; ++i) {
        accg[i] = __builtin_amdgcn_mfma_f32_16x16x32_bf16(a[i], bgf, accg[i], 0, 0, 0);
        accu[i] = __builtin_amdgcn_mfma_f32_16x16x32_bf16(a[i], buv, accu[i], 0, 0, 0);
      }
      __syncthreads();
    }
    // epilogue: silu(g)*u -> act (bf16)
#pragma unroll
    for (int i = 0; i < 4; ++i) {
      int mrow = g0 + wm * 64 + i * 16 + lh * 4;
#pragma unroll
      for (int r = 0; r < 4; ++r) {
        float gv = accg[i][r], uv = accu[i][r];
        float av = (gv / (1.f + __expf(-gv))) * uv;
        act[(size_t)(mrow + r) * ID + ncol] = f2bf(av);
      }
    }
  }
}

// --------- GEMM2: ybuf += act @ Wd^T, fused f32 staging, k-split 2, atomics ---------
// grid 448 = 56 mt x 4 nt x 2 kh; XCD gets one (nt,kh) -> its Wd slice L2-fits.
__global__ __launch_bounds__(256, 3) void gemm2_kernel(
    const u16* __restrict__ act,
    const float* __restrict__ Wd, const float* __restrict__ Wds,
    const int* __restrict__ tileSeg, float* __restrict__ ybuf) {
  __shared__ __align__(16) u16 Al[2][128 * 32];  // 2x8KB
  __shared__ __align__(16) u16 Bl[2][128 * 40];  // [h][i] 80B rows (pad), 2x10KB
  int lin = blockIdx.x;
  int wg = (lin & 7) * 56 + (lin >> 3);          // chunk 56 = all mt of one (nt,kh)
  int mt = wg % 56;
  int rest = wg / 56;
  int nt = rest & 3, kh = rest >> 2;
  int s = tileSeg[mt];
  if (s < 0) return;
  const float* B = (s < 8) ? Wd + (size_t)s * ID * HD : Wds;  // [I][H]
  int g0 = mt * 128, h0 = nt * 128, kbase = kh * 704;
  int tid = threadIdx.x;
  int w = tid >> 6, lane = tid & 63;
  int wm = w >> 1, wn = w & 1;
  int l15 = lane & 15, lh = lane >> 4;
  int mA = tid >> 2, slot = tid & 3;
  const u16* srcA[2];
#pragma unroll
  for (int c = 0; c < 2; ++c) {
    int m = c * 64 + mA;
    srcA[c] = act + (size_t)(g0 + m) * ID + kbase + (slot ^ (m & 3)) * 8;
  }
  int hB = tid & 127, ib = tid >> 7;
  float breg[16];
  auto LOADB = [&](int kt) {
#pragma unroll
    for (int j = 0; j < 16; ++j)
      breg[j] = B[(size_t)(kbase + kt * 32 + ib * 16 + j) * HD + h0 + hB];
  };
  auto WRITEB = [&](int nb) {
#pragma unroll
    for (int jj = 0; jj < 2; ++jj) {
      bf16x8 v;
#pragma unroll
      for (int q = 0; q < 8; ++q) v[q] = (__bf16)breg[jj * 8 + q];
      *(bf16x8*)((char*)Bl[nb] + hB * 80 + ib * 32 + jj * 16) = v;
    }
  };
  auto STAGEA = [&](int nb, int kt) {
    int ko = kt * 32;
#pragma unroll
    for (int c = 0; c < 2; ++c)
      gll16(srcA[c] + ko, (char*)Al[nb] + c * 4096 + w * 1024);
  };

  f32x4 acc[4][4];
  f32x4 zz = {0.f, 0.f, 0.f, 0.f};
#pragma unroll
  for (int i = 0; i < 4; ++i)
#pragma unroll
    for (int j = 0; j < 4; ++j) acc[i][j] = zz;

  LOADB(0);
  STAGEA(0, 0);
  WRITEB(0);
  __syncthreads();
  for (int kt = 0; kt < 22; ++kt) {
    int cb = kt & 1;
    if (kt < 21) { LOADB(kt + 1); STAGEA(cb ^ 1, kt + 1); }
    bf16x8 a[4], b[4];
#pragma unroll
    for (int i = 0; i < 4; ++i) {
      int mloc = wm * 64 + i * 16 + l15;
      a[i] = *(const bf16x8*)((char*)Al[cb] + ((mloc * 64 + lh * 16) ^ ((mloc & 3) << 4)));
    }
#pragma unroll
    for (int j = 0; j < 4; ++j) {
      int hloc = wn * 64 + j * 16 + l15;
      b[j] = *(const bf16x8*)((char*)Bl[cb] + hloc * 80 + lh * 16);
    }
#pragma unroll
    for (int i = 0; i < 4; ++i)
#pragma unroll
      for (int j = 0; j < 4; ++j)
        acc[i][j] = __builtin_amdgcn_mfma_f32_16x16x32_bf16(a[i], b[j], acc[i][j], 0, 0, 0);
    if (kt < 21) WRITEB(cb ^ 1);
    __syncthreads();
  }
#pragma unroll
  for (int i = 0; i < 4; ++i)
#pragma unroll
    for (int j = 0; j < 4; ++j) {
      int col = h0 + wn * 64 + j * 16 + l15;
#pragma unroll
      for (int r = 0; r < 4; ++r) {
        int row = g0 + wm * 64 + i * 16 + lh * 4 + r;
        atomicAdd(&ybuf[(size_t)row * HD + col], acc[i][j][r]);
      }
    }
}

// --------- combine: out[t] = w0*y(pair0) + w1*y(pair1) + y(shared) ---------
__global__ void combine_kernel(const float* __restrict__ ybuf, const float* __restrict__ topw,
                               const int* __restrict__ inv, float* __restrict__ out) {
  int t = blockIdx.x;
  int hd = threadIdx.x;  // 128 float4 lanes
  int i0 = inv[t * 2], i1 = inv[t * 2 + 1];
  float w0 = topw[t * 2], w1 = topw[t * 2 + 1];
  const float4* y4 = (const float4*)ybuf;
  float4 a = y4[(size_t)i0 * 128 + hd];
  float4 b = y4[(size_t)i1 * 128 + hd];
  float4 c = y4[(size_t)(SHOFF + t) * 128 + hd];
  float4 o;
  o.x = w0 * a.x + w1 * b.x + c.x;
  o.y = w0 * a.y + w1 * b.y + c.y;
  o.z = w0 * a.z + w1 * b.z + c.z;
  o.w = w0 * a.w + w1 * b.w + c.w;
  ((float4*)out)[(size_t)t * 128 + hd] = o;
}

extern "C" void kernel_launch(void* const* d_in, const int* in_sizes, int n_in,
                              void* d_out, int out_size, void* d_ws, size_t ws_size,
                              hipStream_t stream) {
  const float* x   = (const float*)d_in[0];
  const float* gw  = (const float*)d_in[1];
  const float* Wg  = (const float*)d_in[2];
  const float* Wu  = (const float*)d_in[3];
  const float* Wd  = (const float*)d_in[4];
  const float* Wgs = (const float*)d_in[5];
  const float* Wus = (const float*)d_in[6];
  const float* Wds = (const float*)d_in[7];
  float* out = (float*)d_out;

  if (ws_size < (size_t)40 * 1024 * 1024) return;

  char* ws = (char*)d_ws;
  size_t o = 0;
  auto alloc = [&](size_t bytes) { char* p = ws + o; o += (bytes + 255) & ~(size_t)255; return p; };
  u16* Xg      = (u16*)alloc((size_t)NTOK * HD * 2);
  u16* act     = (u16*)alloc((size_t)TOTROWS * ID * 2);
  float* ybuf  = (float*)alloc((size_t)TOTROWS * HD * 4);
  float* scores = (float*)alloc((size_t)NTOK * 8 * 4);
  float* topw   = (float*)alloc((size_t)NTOK * 2 * 4);
  int* topidx   = (int*)alloc((size_t)NTOK * 2 * 4);
  int* pairTok  = (int*)alloc((size_t)PADCAP * 4);
  int* inv      = (int*)alloc((size_t)NPAIRS * 4);
  int* segTileStart = (int*)alloc(64);
  int* tileSeg      = (int*)alloc(256);

  gate_kernel<<<NTOK / 4, 256, 0, stream>>>(x, gw, Xg, scores, topw, topidx);
  scatter_kernel<<<1, 1024, 0, stream>>>(topidx, scores, pairTok, inv,
                                         segTileStart, tileSeg, out + (size_t)NTOK * HD);
  hipMemsetAsync(ybuf, 0, (size_t)TOTROWS * HD * 4, stream);
  gemm1_kernel<<<44 * 12, 256, 0, stream>>>(Xg, Wg, Wu, Wgs, Wus,
                                            pairTok, segTileStart, act);
  gemm2_kernel<<<56 * 4 * 2, 256, 0, stream>>>(act, Wd, Wds, tileSeg, ybuf);
  combine_kernel<<<NTOK, 128, 0, stream>>>(ybuf, topw, inv, out);
}